// Round 1
// baseline (441.850 us; speedup 1.0000x reference)
//
#include <hip/hip_runtime.h>
#include <hip/hip_bf16.h>
#include <stdint.h>

typedef __attribute__((ext_vector_type(8))) short bf16x8;
typedef __attribute__((ext_vector_type(4))) float f32x4;

union FragU { uint4 u; bf16x8 v; };

#define Bn 16
#define Kn 16
#define Sn 512
#define En 512
#define Ln 16
#define Hn 8
#define Dn 64

__device__ __forceinline__ uint32_t pack_bf16(float lo, float hi) {
  uint32_t a = __float_as_uint(lo) + 0x8000u;
  uint32_t b = __float_as_uint(hi) + 0x8000u;
  return __builtin_amdgcn_perm(b, a, 0x07060302u);  // [b.hi16 : a.hi16]
}
__device__ __forceinline__ uint16_t bf16_1(float x) {
  __hip_bfloat16 h = __float2bfloat16(x);
  return *(uint16_t*)&h;
}
__device__ __forceinline__ void gload_lds16(const void* g, void* l) {
  __builtin_amdgcn_global_load_lds(
      (const __attribute__((address_space(1))) uint32_t*)g,
      (__attribute__((address_space(3))) uint32_t*)l, 16, 0, 0);
}

// ---------------- Kernel 0: fused prep ----------------
// blocks 0..511   : xq = latent_query @ Wq^T (column j = blockIdx)
// blocks 512..575 : Wk/Wv -> Wsw (bf16, XOR bank swizzle baked in)
// blocks 576..703 : Wo -> Wob (bf16 row-major)
__global__ __launch_bounds__(256)
void prep_kernel(const float* __restrict__ latent, const float* __restrict__ Wq,
                 const float* __restrict__ Wk, const float* __restrict__ Wv,
                 const float* __restrict__ Wo,
                 float* __restrict__ xq, uint4* __restrict__ Wsw, uint4* __restrict__ Wob)
{
  __shared__ float red[4][Ln];
  const int t = threadIdx.x;
  const int blk = blockIdx.x;
  if (blk < 512) {
    const int j = blk;
    const float w0 = Wq[j*En + t];
    const float w1 = Wq[j*En + t + 256];
    float part[Ln];
#pragma unroll
    for (int l = 0; l < Ln; ++l)
      part[l] = w0 * latent[l*En + t] + w1 * latent[l*En + t + 256];
#pragma unroll
    for (int l = 0; l < Ln; ++l) {
      float v = part[l];
#pragma unroll
      for (int off = 32; off > 0; off >>= 1) v += __shfl_down(v, off, 64);
      part[l] = v;
    }
    const int lane = t & 63, wv = t >> 6;
    if (lane == 0) {
#pragma unroll
      for (int l = 0; l < Ln; ++l) red[wv][l] = part[l];
    }
    __syncthreads();
    if (t < Ln)
      xq[t*En + j] = red[0][t] + red[1][t] + red[2][t] + red[3][t];
  } else if (blk < 576) {
    const int idx = (blk - 512)*256 + t;
    const int kb = idx >> 11;
    const int rem = idx & 2047;
    const int n = rem >> 3, p = rem & 7;
    const int c = p ^ (n & 7);
    const float* src = (n < 128 ? Wk + (size_t)n*En : Wv + (size_t)(n-128)*En) + kb*64 + c*8;
    float4 v0 = *(const float4*)src;
    float4 v1 = *(const float4*)(src+4);
    uint4 o;
    o.x = pack_bf16(v0.x,v0.y); o.y = pack_bf16(v0.z,v0.w);
    o.z = pack_bf16(v1.x,v1.y); o.w = pack_bf16(v1.z,v1.w);
    Wsw[idx] = o;
  } else {
    const int idx = (blk - 576)*256 + t;
    const float* src = Wo + (size_t)idx*8;
    float4 v0 = *(const float4*)src;
    float4 v1 = *(const float4*)(src+4);
    uint4 o;
    o.x = pack_bf16(v0.x,v0.y); o.y = pack_bf16(v0.z,v0.w);
    o.z = pack_bf16(v1.x,v1.y); o.w = pack_bf16(v1.z,v1.w);
    Wob[idx] = o;
  }
}

// ---------------- Kernel 1: KV projection, 64m x 256n, BK=64, ragged early-exit ----------------
// T14+T4: spike tile for step kb+1 is prefetched to registers and left in flight
// across the MFMA phase via a counted s_waitcnt vmcnt(4) barrier (the 8 weight
// global_load_lds are the oldest vmcnt entries, so vmcnt(4) retires exactly them).
__global__ __launch_bounds__(256, 3)
void kvproj_kernel(const float* __restrict__ spike, const int* __restrict__ offsets,
                   const float* __restrict__ cosT, const float* __restrict__ sinT,
                   const uint4* __restrict__ Wsw, const int* __restrict__ lengths,
                   uint16_t* __restrict__ Kbuf, uint16_t* __restrict__ Vt)
{
  __shared__ __align__(16) uint16_t Bs[256*64];   // 32 KB, swizzled rows
  __shared__ __align__(16) uint16_t As[64*72];    // 9 KB, rows 64 bf16 + 8 pad
  const int t = threadIdx.x;
  const int bk   = blockIdx.x >> 3;
  const int tile = blockIdx.x & 7;
  if (tile * 64 >= lengths[bk]) return;   // rows s>=len never read downstream
  const int m0 = blockIdx.x * 64;
  const int lane = t & 63, wv = t >> 6;
  const int quad = lane >> 4, lr = lane & 15;

  f32x4 acc[4][4];
#pragma unroll
  for (int i=0;i<4;i++)
#pragma unroll
    for (int j=0;j<4;j++) acc[i][j] = (f32x4){0.f,0.f,0.f,0.f};

  const int arow = t >> 3;
  const int aseg = t & 7;

  // prologue: prefetch spike tile for kb=0
  float4 pf[4];
  {
    const float* s0p = &spike[(size_t)(m0+arow)*En + aseg*8];
    pf[0] = *(const float4*)s0p; pf[1] = *(const float4*)(s0p+4);
    const float* s1p = &spike[(size_t)(m0+arow+32)*En + aseg*8];
    pf[2] = *(const float4*)s1p; pf[3] = *(const float4*)(s1p+4);
  }

  for (int kb = 0; kb < 8; ++kb) {
    // (a) weight staging first: 8 global_load_lds (oldest vmcnt entries)
    const char* gb = (const char*)(Wsw + kb*2048) + (wv*64 + lane)*16;
    char* lb = (char*)Bs + wv*1024;
#pragma unroll
    for (int i = 0; i < 8; ++i)
      gload_lds16(gb + i*4096, lb + i*4096);

    // (b) consume current spike regs -> As (compiler waits vmcnt for pf only)
    {
      uint4 o;
      o.x = pack_bf16(pf[0].x,pf[0].y); o.y = pack_bf16(pf[0].z,pf[0].w);
      o.z = pack_bf16(pf[1].x,pf[1].y); o.w = pack_bf16(pf[1].z,pf[1].w);
      *(uint4*)&As[arow*72 + aseg*8] = o;
      uint4 p;
      p.x = pack_bf16(pf[2].x,pf[2].y); p.y = pack_bf16(pf[2].z,pf[2].w);
      p.z = pack_bf16(pf[3].x,pf[3].y); p.w = pack_bf16(pf[3].z,pf[3].w);
      *(uint4*)&As[(arow+32)*72 + aseg*8] = p;
    }

    // (c) prefetch next spike tile (must be issued AFTER the 8 gloads)
    __builtin_amdgcn_sched_barrier(0);
    if (kb < 7) {
      const float* s0p = &spike[(size_t)(m0+arow)*En + (kb+1)*64 + aseg*8];
      pf[0] = *(const float4*)s0p; pf[1] = *(const float4*)(s0p+4);
      const float* s1p = &spike[(size_t)(m0+arow+32)*En + (kb+1)*64 + aseg*8];
      pf[2] = *(const float4*)s1p; pf[3] = *(const float4*)(s1p+4);
      asm volatile("s_waitcnt vmcnt(4) lgkmcnt(0)" ::: "memory");
    } else {
      asm volatile("s_waitcnt vmcnt(0) lgkmcnt(0)" ::: "memory");
    }
    __builtin_amdgcn_s_barrier();
    __builtin_amdgcn_sched_barrier(0);

    // (d) compute
#pragma unroll
    for (int kk = 0; kk < 2; ++kk) {
      const int c = kk*4 + quad;
      FragU aF[4], bF[4];
#pragma unroll
      for (int mi=0;mi<4;mi++) aF[mi].u = *(const uint4*)&As[(mi*16+lr)*72 + c*8];
#pragma unroll
      for (int ni=0;ni<4;ni++) {
        const int n = wv*64 + ni*16 + lr;
        bF[ni].u = *(const uint4*)&Bs[n*64 + (c ^ (n&7))*8];
      }
#pragma unroll
      for (int mi=0;mi<4;mi++)
#pragma unroll
        for (int ni=0;ni<4;ni++)
          acc[mi][ni] = __builtin_amdgcn_mfma_f32_16x16x32_bf16(aF[mi].v, bF[ni].v, acc[mi][ni], 0,0,0);
    }

    // (e) barrier-2: lgkm only — prefetch loads stay in flight
    asm volatile("s_waitcnt lgkmcnt(0)" ::: "memory");
    __builtin_amdgcn_s_barrier();
    __builtin_amdgcn_sched_barrier(0);
  }

  const int sbase = m0 & 511;
  if (wv < 2) {
#pragma unroll
    for (int mi=0;mi<4;mi++) {
#pragma unroll
      for (int r=0;r<4;r++) {
        const int s = sbase + mi*16 + quad*4 + r;
        const int off = offsets[m0 + mi*16 + quad*4 + r];
#pragma unroll
        for (int ni=0;ni<4;ni++) {
          const int d = ni*16 + lr;
          const float v = acc[mi][ni][r];
          const float p = acc[mi][ni^2][r];
          const float rot = (ni < 2) ? -p : p;
          const float cc  = cosT[off*Dn + d];
          const float sn  = sinT[off*Dn + d];
          Kbuf[((size_t)(bk*512 + s))*128 + wv*64 + d] = bf16_1(v*cc + rot*sn);
        }
      }
    }
  } else {
    const int nbase = (wv - 2) * 64;
#pragma unroll
    for (int mi=0;mi<4;mi++) {
#pragma unroll
      for (int ni=0;ni<4;ni++) {
        const int np = nbase + ni*16 + lr;
        const int s  = sbase + mi*16 + quad*4;
        uint2 pk;
        pk.x = pack_bf16(acc[mi][ni][0], acc[mi][ni][1]);
        pk.y = pack_bf16(acc[mi][ni][2], acc[mi][ni][3]);
        *(uint2*)&Vt[((size_t)(bk*128 + np))*512 + s] = pk;
      }
    }
  }
}

// ---------------- Kernel 2: flash attention, one block per (bk, kvh), wave = head ----------------
// T14: next chunk's K/V prefetched into a second register set during compute;
// the mid-chunk barrier waits lgkmcnt(0) only, leaving the 8 loads in flight.
// T5: s_setprio(1) around MFMA clusters (attn-positive per m191).
__global__ __launch_bounds__(256)
void attn_kernel(const float* __restrict__ xq, const uint16_t* __restrict__ Kbuf,
                 const uint16_t* __restrict__ Vt, const int* __restrict__ lengths,
                 uint16_t* __restrict__ attn_out)
{
  __shared__ __align__(16) uint16_t Ks [128*72];
  __shared__ __align__(16) uint16_t Vts[64*136];
  __shared__ __align__(16) uint16_t Ps [4*16*136];

  const int t = threadIdx.x;
  const int bk = blockIdx.x >> 1, kvh = blockIdx.x & 1;
  const int w = t >> 6, lane = t & 63;
  const int quad = lane >> 4, lr = lane & 15;
  const int h = kvh*4 + w;
  const int len = lengths[bk];
  const int nc = (len + 127) >> 7;   // 1..4

  FragU aQ[2];
#pragma unroll
  for (int kk=0;kk<2;kk++) {
    const float* qp = &xq[lr*En + h*Dn + kk*32 + quad*8];
    float4 q0 = *(const float4*)qp;
    float4 q1 = *(const float4*)(qp + 4);
    aQ[kk].u.x = pack_bf16(q0.x*0.125f, q0.y*0.125f);
    aQ[kk].u.y = pack_bf16(q0.z*0.125f, q0.w*0.125f);
    aQ[kk].u.z = pack_bf16(q1.x*0.125f, q1.y*0.125f);
    aQ[kk].u.w = pack_bf16(q1.z*0.125f, q1.w*0.125f);
  }

  float m_run[4], l_run[4], alpha[4];
  f32x4 oacc[4];
#pragma unroll
  for (int r=0;r<4;r++){ m_run[r] = -3.0e38f; l_run[r] = 0.f; }
#pragma unroll
  for (int nd=0;nd<4;nd++) oacc[nd] = (f32x4){0.f,0.f,0.f,0.f};

  const int krow = t >> 1, kseg = t & 1;
  const int vrow = t >> 2, vseg = t & 3;
  const uint16_t* gK = &Kbuf[((size_t)(bk*512 + krow))*128 + kvh*64 + kseg*32];
  const uint16_t* gV = &Vt [((size_t)(bk*128 + kvh*64 + vrow))*512 + vseg*32];

  auto pref = [&](int c, uint4* r) {
    const uint16_t* g  = gK + (size_t)c*16384;   // +128 rows * 128 halves
    r[0] = *(const uint4*)g;      r[1] = *(const uint4*)(g+8);
    r[2] = *(const uint4*)(g+16); r[3] = *(const uint4*)(g+24);
    const uint16_t* gv = gV + c*128;             // +128 cols
    r[4] = *(const uint4*)gv;      r[5] = *(const uint4*)(gv+8);
    r[6] = *(const uint4*)(gv+16); r[7] = *(const uint4*)(gv+24);
  };
  auto stage = [&](const uint4* r) {
    uint16_t* dst = &Ks[krow*72 + kseg*32];
    *(uint4*)dst = r[0]; *(uint4*)(dst+8) = r[1];
    *(uint4*)(dst+16) = r[2]; *(uint4*)(dst+24) = r[3];
    uint16_t* dv = &Vts[vrow*136 + vseg*32];
    *(uint4*)dv = r[4]; *(uint4*)(dv+8) = r[5];
    *(uint4*)(dv+16) = r[6]; *(uint4*)(dv+24) = r[7];
  };

  auto compute_chunk = [&](int c) {
    const int s0 = c * 128;
    f32x4 sc[8];
    __builtin_amdgcn_s_setprio(1);
#pragma unroll
    for (int ni=0;ni<8;ni++) {
      FragU b0, b1;
      b0.u = *(const uint4*)&Ks[(ni*16+lr)*72 + quad*8];
      b1.u = *(const uint4*)&Ks[(ni*16+lr)*72 + 32 + quad*8];
      f32x4 a = (f32x4){0.f,0.f,0.f,0.f};
      a = __builtin_amdgcn_mfma_f32_16x16x32_bf16(aQ[0].v, b0.v, a, 0,0,0);
      a = __builtin_amdgcn_mfma_f32_16x16x32_bf16(aQ[1].v, b1.v, a, 0,0,0);
      sc[ni] = a;
    }
    __builtin_amdgcn_s_setprio(0);
#pragma unroll
    for (int ni=0;ni<8;ni++)
      if (s0 + ni*16 + lr >= len)
        sc[ni] = (f32x4){-3.0e38f,-3.0e38f,-3.0e38f,-3.0e38f};

#pragma unroll
    for (int r=0;r<4;r++) {
      float mx = sc[0][r];
#pragma unroll
      for (int ni=1;ni<8;ni++) mx = fmaxf(mx, sc[ni][r]);
#pragma unroll
      for (int o=1;o<16;o<<=1) mx = fmaxf(mx, __shfl_xor(mx, o, 16));
      const float mnew = fmaxf(m_run[r], mx);
      alpha[r] = __expf(m_run[r] - mnew);
      m_run[r] = mnew;
      float ssum = 0.f;
#pragma unroll
      for (int ni=0;ni<8;ni++) {
        float p = __expf(sc[ni][r] - mnew);
        sc[ni][r] = p;
        ssum += p;
      }
#pragma unroll
      for (int o=1;o<16;o<<=1) ssum += __shfl_xor(ssum, o, 16);
      l_run[r] = l_run[r]*alpha[r] + ssum;
    }

#pragma unroll
    for (int ni=0;ni<8;ni++)
#pragma unroll
      for (int r=0;r<4;r++)
        Ps[(w*16 + quad*4 + r)*136 + ni*16 + lr] = bf16_1(sc[ni][r]);

#pragma unroll
    for (int nd=0;nd<4;nd++)
#pragma unroll
      for (int r=0;r<4;r++) oacc[nd][r] *= alpha[r];

    __builtin_amdgcn_s_setprio(1);
#pragma unroll
    for (int kk=0;kk<4;kk++) {
      FragU aP;
      aP.u = *(const uint4*)&Ps[(w*16 + lr)*136 + kk*32 + quad*8];
#pragma unroll
      for (int nd=0;nd<4;nd++) {
        FragU bV;
        bV.u = *(const uint4*)&Vts[(nd*16+lr)*136 + kk*32 + quad*8];
        oacc[nd] = __builtin_amdgcn_mfma_f32_16x16x32_bf16(aP.v, bV.v, oacc[nd], 0,0,0);
      }
    }
    __builtin_amdgcn_s_setprio(0);
  };

  auto run_chunk = [&](int c, uint4* cur, uint4* nxt) {
    __syncthreads();                 // prev chunk's LDS reads done (also drains prefetch, now needed)
    stage(cur);
    if (c + 1 < nc) pref(c + 1, nxt);
    asm volatile("s_waitcnt lgkmcnt(0)" ::: "memory");   // ds_writes visible; vmcnt untouched
    __builtin_amdgcn_s_barrier();
    __builtin_amdgcn_sched_barrier(0);
    compute_chunk(c);
  };

  uint4 bufA[8], bufB[8];
  pref(0, bufA);
  run_chunk(0, bufA, bufB);
  if (nc > 1) run_chunk(1, bufB, bufA);
  if (nc > 2) run_chunk(2, bufA, bufB);
  if (nc > 3) run_chunk(3, bufB, bufA);

#pragma unroll
  for (int r=0;r<4;r++) {
    const float rs = 1.0f / l_run[r];
    const int l = quad*4 + r;
#pragma unroll
    for (int nd=0;nd<4;nd++)
      attn_out[((size_t)(bk*16 + l))*512 + h*64 + nd*16 + lr] = bf16_1(oacc[nd][r] * rs);
  }
}

// ---------------- Kernel 3: out = attn_out(4096x512,bf16) @ Wob^T ----------------
// Retiled 128x128 -> 64x64 (128 -> 512 blocks) so all 256 CUs are busy;
// same register-prefetch + counted-wait staging as kvproj.
__global__ __launch_bounds__(256)
void oproj_kernel(const uint16_t* __restrict__ Ab, const uint16_t* __restrict__ Wob,
                  float* __restrict__ out)
{
  __shared__ __align__(16) uint16_t As[64*72];
  __shared__ __align__(16) uint16_t Bs[64*72];
  const int t = threadIdx.x;
  const int m0 = (blockIdx.x >> 3) * 64;
  const int n0 = (blockIdx.x & 7) * 64;
  const int lane = t & 63, wv = t >> 6;
  const int quad = lane >> 4, lr = lane & 15;
  const int wm = wv >> 1, wn = wv & 1;

  f32x4 acc[2][2];
#pragma unroll
  for (int i=0;i<2;i++)
#pragma unroll
    for (int j=0;j<2;j++) acc[i][j] = (f32x4){0.f,0.f,0.f,0.f};

  const int srow = t >> 3, sseg = t & 7;

  uint4 pa[2], pb[2];
#pragma unroll
  for (int j = 0; j < 2; ++j) {
    const int row = srow + 32*j;
    pa[j] = *(const uint4*)&Ab [(size_t)(m0+row)*512 + sseg*8];
    pb[j] = *(const uint4*)&Wob[(size_t)(n0+row)*512 + sseg*8];
  }

  for (int kb = 0; kb < 8; ++kb) {
#pragma unroll
    for (int j = 0; j < 2; ++j) {
      const int row = srow + 32*j;
      *(uint4*)&As[row*72 + sseg*8] = pa[j];
      *(uint4*)&Bs[row*72 + sseg*8] = pb[j];
    }
    __builtin_amdgcn_sched_barrier(0);
    if (kb < 7) {
#pragma unroll
      for (int j = 0; j < 2; ++j) {
        const int row = srow + 32*j;
        pa[j] = *(const uint4*)&Ab [(size_t)(m0+row)*512 + (kb+1)*64 + sseg*8];
        pb[j] = *(const uint4*)&Wob[(size_t)(n0+row)*512 + (kb+1)*64 + sseg*8];
      }
    }
    asm volatile("s_waitcnt lgkmcnt(0)" ::: "memory");   // prefetch loads stay in flight
    __builtin_amdgcn_s_barrier();
    __builtin_amdgcn_sched_barrier(0);
#pragma unroll
    for (int kk = 0; kk < 2; ++kk) {
      const int c = kk*4 + quad;
      FragU aF[2], bF[2];
#pragma unroll
      for (int mi=0;mi<2;mi++) aF[mi].u = *(const uint4*)&As[(wm*32+mi*16+lr)*72 + c*8];
#pragma unroll
      for (int ni=0;ni<2;ni++) bF[ni].u = *(const uint4*)&Bs[(wn*32+ni*16+lr)*72 + c*8];
#pragma unroll
      for (int mi=0;mi<2;mi++)
#pragma unroll
        for (int ni=0;ni<2;ni++)
          acc[mi][ni] = __builtin_amdgcn_mfma_f32_16x16x32_bf16(aF[mi].v, bF[ni].v, acc[mi][ni], 0,0,0);
    }
    asm volatile("s_waitcnt lgkmcnt(0)" ::: "memory");
    __builtin_amdgcn_s_barrier();
    __builtin_amdgcn_sched_barrier(0);
  }
#pragma unroll
  for (int mi=0;mi<2;mi++)
#pragma unroll
    for (int r=0;r<4;r++)
#pragma unroll
      for (int ni=0;ni<2;ni++)
        out[(size_t)(m0 + wm*32 + mi*16 + quad*4 + r)*512 + n0 + wn*32 + ni*16 + lr] = acc[mi][ni][r];
}

// ---------------- launch ----------------
extern "C" void kernel_launch(void* const* d_in, const int* in_sizes, int n_in,
                              void* d_out, int out_size, void* d_ws, size_t ws_size,
                              hipStream_t stream)
{
  const float* spike   = (const float*)d_in[0];
  const int*   offsets = (const int*)d_in[1];
  const int*   lengths = (const int*)d_in[2];
  const float* cosT    = (const float*)d_in[3];
  const float* sinT    = (const float*)d_in[4];
  const float* latent  = (const float*)d_in[5];
  const float* Wq      = (const float*)d_in[6];
  const float* Wk      = (const float*)d_in[7];
  const float* Wv      = (const float*)d_in[8];
  const float* Wo      = (const float*)d_in[9];
  float* out = (float*)d_out;

  char* ws = (char*)d_ws;
  float*    xq   = (float*)ws;                                  // 64 KB reserved
  uint4*    Wsw  = (uint4*)(ws + 65536);                        // 256 KB
  uint4*    Wob  = (uint4*)(ws + 65536 + 262144);               // 512 KB
  uint16_t* Kbuf = (uint16_t*)(ws + 1048576);                   // 32 MB
  uint16_t* Vt   = (uint16_t*)(ws + 1048576 + 33554432ull);     // 32 MB
  uint16_t* attn_out = (uint16_t*)(ws + 1048576 + 67108864ull); // 4 MB

  hipLaunchKernelGGL(prep_kernel,   dim3(704),  dim3(256), 0, stream,
                     latent, Wq, Wk, Wv, Wo, xq, Wsw, Wob);
  hipLaunchKernelGGL(kvproj_kernel, dim3(2048), dim3(256), 0, stream,
                     spike, offsets, cosT, sinT, Wsw, lengths, Kbuf, Vt);
  hipLaunchKernelGGL(attn_kernel,   dim3(512),  dim3(256), 0, stream,
                     xq, Kbuf, Vt, lengths, attn_out);
  hipLaunchKernelGGL(oproj_kernel,  dim3(512),  dim3(256), 0, stream,
                     attn_out, (const uint16_t*)Wob, out);
}

// Round 4
// 427.550 us; speedup vs baseline: 1.0334x; 1.0334x over previous
//
#include <hip/hip_runtime.h>
#include <hip/hip_bf16.h>
#include <stdint.h>

typedef __attribute__((ext_vector_type(8))) short bf16x8;
typedef __attribute__((ext_vector_type(4))) float f32x4;

union FragU { uint4 u; bf16x8 v; };

#define Bn 16
#define Kn 16
#define Sn 512
#define En 512
#define Ln 16
#define Hn 8
#define Dn 64

__device__ __forceinline__ uint32_t pack_bf16(float lo, float hi) {
  uint32_t a = __float_as_uint(lo) + 0x8000u;
  uint32_t b = __float_as_uint(hi) + 0x8000u;
  return __builtin_amdgcn_perm(b, a, 0x07060302u);  // [b.hi16 : a.hi16]
}
__device__ __forceinline__ uint16_t bf16_1(float x) {
  __hip_bfloat16 h = __float2bfloat16(x);
  return *(uint16_t*)&h;
}
__device__ __forceinline__ void gload_lds16(const void* g, void* l) {
  __builtin_amdgcn_global_load_lds(
      (const __attribute__((address_space(1))) uint32_t*)g,
      (__attribute__((address_space(3))) uint32_t*)l, 16, 0, 0);
}

// ---------------- Kernel 0: fused prep ----------------
// blocks 0..511   : xq = latent_query @ Wq^T (column j = blockIdx)
// blocks 512..575 : Wk/Wv -> Wsw (bf16, XOR bank swizzle baked in)
// blocks 576..703 : Wo -> Wob (bf16 row-major)
__global__ __launch_bounds__(256)
void prep_kernel(const float* __restrict__ latent, const float* __restrict__ Wq,
                 const float* __restrict__ Wk, const float* __restrict__ Wv,
                 const float* __restrict__ Wo,
                 float* __restrict__ xq, uint4* __restrict__ Wsw, uint4* __restrict__ Wob)
{
  __shared__ float red[4][Ln];
  const int t = threadIdx.x;
  const int blk = blockIdx.x;
  if (blk < 512) {
    const int j = blk;
    const float w0 = Wq[j*En + t];
    const float w1 = Wq[j*En + t + 256];
    float part[Ln];
#pragma unroll
    for (int l = 0; l < Ln; ++l)
      part[l] = w0 * latent[l*En + t] + w1 * latent[l*En + t + 256];
#pragma unroll
    for (int l = 0; l < Ln; ++l) {
      float v = part[l];
#pragma unroll
      for (int off = 32; off > 0; off >>= 1) v += __shfl_down(v, off, 64);
      part[l] = v;
    }
    const int lane = t & 63, wv = t >> 6;
    if (lane == 0) {
#pragma unroll
      for (int l = 0; l < Ln; ++l) red[wv][l] = part[l];
    }
    __syncthreads();
    if (t < Ln)
      xq[t*En + j] = red[0][t] + red[1][t] + red[2][t] + red[3][t];
  } else if (blk < 576) {
    const int idx = (blk - 512)*256 + t;
    const int kb = idx >> 11;
    const int rem = idx & 2047;
    const int n = rem >> 3, p = rem & 7;
    const int c = p ^ (n & 7);
    const float* src = (n < 128 ? Wk + (size_t)n*En : Wv + (size_t)(n-128)*En) + kb*64 + c*8;
    float4 v0 = *(const float4*)src;
    float4 v1 = *(const float4*)(src+4);
    uint4 o;
    o.x = pack_bf16(v0.x,v0.y); o.y = pack_bf16(v0.z,v0.w);
    o.z = pack_bf16(v1.x,v1.y); o.w = pack_bf16(v1.z,v1.w);
    Wsw[idx] = o;
  } else {
    const int idx = (blk - 576)*256 + t;
    const float* src = Wo + (size_t)idx*8;
    float4 v0 = *(const float4*)src;
    float4 v1 = *(const float4*)(src+4);
    uint4 o;
    o.x = pack_bf16(v0.x,v0.y); o.y = pack_bf16(v0.z,v0.w);
    o.z = pack_bf16(v1.x,v1.y); o.w = pack_bf16(v1.z,v1.w);
    Wob[idx] = o;
  }
}

// ---------------- Kernel 1: KV projection (round-0 proven version) ----------------
__global__ __launch_bounds__(256)
void kvproj_kernel(const float* __restrict__ spike, const int* __restrict__ offsets,
                   const float* __restrict__ cosT, const float* __restrict__ sinT,
                   const uint4* __restrict__ Wsw, const int* __restrict__ lengths,
                   uint16_t* __restrict__ Kbuf, uint16_t* __restrict__ Vt)
{
  __shared__ __align__(16) uint16_t Bs[256*64];   // 32 KB, swizzled rows
  __shared__ __align__(16) uint16_t As[64*72];    // 9 KB, rows 64 bf16 + 8 pad
  const int t = threadIdx.x;
  const int bk   = blockIdx.x >> 3;
  const int tile = blockIdx.x & 7;
  // Ragged skip: rows s >= len are never read downstream (scores masked, P=0).
  if (tile * 64 >= lengths[bk]) return;
  const int m0 = blockIdx.x * 64;
  const int lane = t & 63, wv = t >> 6;
  const int quad = lane >> 4, lr = lane & 15;

  f32x4 acc[4][4];
#pragma unroll
  for (int i=0;i<4;i++)
#pragma unroll
    for (int j=0;j<4;j++) acc[i][j] = (f32x4){0.f,0.f,0.f,0.f};

  const int arow = t >> 3;
  const int aseg = t & 7;

  for (int kb = 0; kb < 8; ++kb) {
    const char* gb = (const char*)(Wsw + kb*2048) + (wv*64 + lane)*16;
    char* lb = (char*)Bs + wv*1024;
#pragma unroll
    for (int i = 0; i < 8; ++i)
      gload_lds16(gb + i*4096, lb + i*4096);
#pragma unroll
    for (int j = 0; j < 2; ++j) {
      const int row = arow + 32*j;
      const float* src = &spike[(size_t)(m0+row)*En + kb*64 + aseg*8];
      float4 v0 = *(const float4*)src;
      float4 v1 = *(const float4*)(src+4);
      uint4 o;
      o.x = pack_bf16(v0.x,v0.y); o.y = pack_bf16(v0.z,v0.w);
      o.z = pack_bf16(v1.x,v1.y); o.w = pack_bf16(v1.z,v1.w);
      *(uint4*)&As[row*72 + aseg*8] = o;
    }
    __syncthreads();
#pragma unroll
    for (int kk = 0; kk < 2; ++kk) {
      const int c = kk*4 + quad;
      FragU aF[4], bF[4];
#pragma unroll
      for (int mi=0;mi<4;mi++) aF[mi].u = *(const uint4*)&As[(mi*16+lr)*72 + c*8];
#pragma unroll
      for (int ni=0;ni<4;ni++) {
        const int n = wv*64 + ni*16 + lr;
        bF[ni].u = *(const uint4*)&Bs[n*64 + (c ^ (n&7))*8];
      }
#pragma unroll
      for (int mi=0;mi<4;mi++)
#pragma unroll
        for (int ni=0;ni<4;ni++)
          acc[mi][ni] = __builtin_amdgcn_mfma_f32_16x16x32_bf16(aF[mi].v, bF[ni].v, acc[mi][ni], 0,0,0);
    }
    __syncthreads();
  }

  const int sbase = m0 & 511;
  if (wv < 2) {
#pragma unroll
    for (int mi=0;mi<4;mi++) {
#pragma unroll
      for (int r=0;r<4;r++) {
        const int s = sbase + mi*16 + quad*4 + r;
        const int off = offsets[m0 + mi*16 + quad*4 + r];
#pragma unroll
        for (int ni=0;ni<4;ni++) {
          const int d = ni*16 + lr;
          const float v = acc[mi][ni][r];
          const float p = acc[mi][ni^2][r];
          const float rot = (ni < 2) ? -p : p;
          const float cc  = cosT[off*Dn + d];
          const float sn  = sinT[off*Dn + d];
          Kbuf[((size_t)(bk*512 + s))*128 + wv*64 + d] = bf16_1(v*cc + rot*sn);
        }
      }
    }
  } else {
    const int nbase = (wv - 2) * 64;
#pragma unroll
    for (int mi=0;mi<4;mi++) {
#pragma unroll
      for (int ni=0;ni<4;ni++) {
        const int np = nbase + ni*16 + lr;
        const int s  = sbase + mi*16 + quad*4;
        uint2 pk;
        pk.x = pack_bf16(acc[mi][ni][0], acc[mi][ni][1]);
        pk.y = pack_bf16(acc[mi][ni][2], acc[mi][ni][3]);
        *(uint2*)&Vt[((size_t)(bk*128 + np))*512 + s] = pk;
      }
    }
  }
}

// ---------------- Kernel 2: flash attention ----------------
// T14 prefetch with NAMED uint4 registers (no arrays -> no scratch risk, rule #20).
// Single reg set: ds_writes consume the regs before the next-chunk loads redefine
// them (WAR, legal); compiler places its vmcnt wait right before the ds_writes,
// i.e. AFTER the previous chunk's compute -> loads overlap QK/softmax/PV.
// Mid-chunk barrier waits lgkmcnt(0) only so prefetch loads stay in flight.
__global__ __launch_bounds__(256)
void attn_kernel(const float* __restrict__ xq, const uint16_t* __restrict__ Kbuf,
                 const uint16_t* __restrict__ Vt, const int* __restrict__ lengths,
                 uint16_t* __restrict__ attn_out)
{
  __shared__ __align__(16) uint16_t Ks [128*72];
  __shared__ __align__(16) uint16_t Vts[64*136];
  __shared__ __align__(16) uint16_t Ps [4*16*136];

  const int t = threadIdx.x;
  const int bk = blockIdx.x >> 1, kvh = blockIdx.x & 1;
  const int w = t >> 6, lane = t & 63;
  const int quad = lane >> 4, lr = lane & 15;
  const int h = kvh*4 + w;
  const int len = lengths[bk];
  const int nc = (len + 127) >> 7;   // 1..4 chunks of 128

  FragU aQ[2];
#pragma unroll
  for (int kk=0;kk<2;kk++) {
    const float* qp = &xq[lr*En + h*Dn + kk*32 + quad*8];
    float4 q0 = *(const float4*)qp;
    float4 q1 = *(const float4*)(qp + 4);
    aQ[kk].u.x = pack_bf16(q0.x*0.125f, q0.y*0.125f);
    aQ[kk].u.y = pack_bf16(q0.z*0.125f, q0.w*0.125f);
    aQ[kk].u.z = pack_bf16(q1.x*0.125f, q1.y*0.125f);
    aQ[kk].u.w = pack_bf16(q1.z*0.125f, q1.w*0.125f);
  }

  float m_run[4], l_run[4], alpha[4];
  f32x4 oacc[4];
#pragma unroll
  for (int r=0;r<4;r++){ m_run[r] = -3.0e38f; l_run[r] = 0.f; }
#pragma unroll
  for (int nd=0;nd<4;nd++) oacc[nd] = (f32x4){0.f,0.f,0.f,0.f};

  const int krow = t >> 1, kseg = t & 1;
  const int vrow = t >> 2, vseg = t & 3;
  const uint16_t* gK = &Kbuf[((size_t)(bk*512 + krow))*128 + kvh*64 + kseg*32];
  const uint16_t* gV = &Vt [((size_t)(bk*128 + kvh*64 + vrow))*512 + vseg*32];

  uint4 k0, k1, k2, k3, v0, v1, v2, v3;   // named -> guaranteed VGPRs

#define PREF(c) do {                                           \
    const uint16_t* g_  = gK + (size_t)(c)*16384;              \
    k0 = *(const uint4*)g_;      k1 = *(const uint4*)(g_+8);   \
    k2 = *(const uint4*)(g_+16); k3 = *(const uint4*)(g_+24);  \
    const uint16_t* gv_ = gV + (c)*128;                        \
    v0 = *(const uint4*)gv_;      v1 = *(const uint4*)(gv_+8); \
    v2 = *(const uint4*)(gv_+16); v3 = *(const uint4*)(gv_+24);\
  } while(0)

  PREF(0);

  for (int c = 0; c < nc; ++c) {
    const int s0 = c * 128;
    __syncthreads();   // prev chunk's LDS reads done; also waits chunk-c loads
    {
      uint16_t* dst = &Ks[krow*72 + kseg*32];
      *(uint4*)dst = k0; *(uint4*)(dst+8) = k1;
      *(uint4*)(dst+16) = k2; *(uint4*)(dst+24) = k3;
      uint16_t* dv = &Vts[vrow*136 + vseg*32];
      *(uint4*)dv = v0; *(uint4*)(dv+8) = v1;
      *(uint4*)(dv+16) = v2; *(uint4*)(dv+24) = v3;
    }
    if (c + 1 < nc) PREF(c + 1);               // issue next-chunk loads now
    __builtin_amdgcn_sched_barrier(0);         // keep them above the barrier
    asm volatile("s_waitcnt lgkmcnt(0)" ::: "memory");  // ds_writes visible; vmcnt untouched
    __builtin_amdgcn_s_barrier();
    __builtin_amdgcn_sched_barrier(0);

    f32x4 sc[8];
    __builtin_amdgcn_s_setprio(1);
#pragma unroll
    for (int ni=0;ni<8;ni++) {
      FragU b0, b1;
      b0.u = *(const uint4*)&Ks[(ni*16+lr)*72 + quad*8];
      b1.u = *(const uint4*)&Ks[(ni*16+lr)*72 + 32 + quad*8];
      f32x4 a = (f32x4){0.f,0.f,0.f,0.f};
      a = __builtin_amdgcn_mfma_f32_16x16x32_bf16(aQ[0].v, b0.v, a, 0,0,0);
      a = __builtin_amdgcn_mfma_f32_16x16x32_bf16(aQ[1].v, b1.v, a, 0,0,0);
      sc[ni] = a;
    }
    __builtin_amdgcn_s_setprio(0);
#pragma unroll
    for (int ni=0;ni<8;ni++)
      if (s0 + ni*16 + lr >= len)
        sc[ni] = (f32x4){-3.0e38f,-3.0e38f,-3.0e38f,-3.0e38f};

#pragma unroll
    for (int r=0;r<4;r++) {
      float mx = sc[0][r];
#pragma unroll
      for (int ni=1;ni<8;ni++) mx = fmaxf(mx, sc[ni][r]);
#pragma unroll
      for (int o=1;o<16;o<<=1) mx = fmaxf(mx, __shfl_xor(mx, o, 16));
      const float mnew = fmaxf(m_run[r], mx);
      alpha[r] = __expf(m_run[r] - mnew);
      m_run[r] = mnew;
      float ssum = 0.f;
#pragma unroll
      for (int ni=0;ni<8;ni++) {
        float p = __expf(sc[ni][r] - mnew);
        sc[ni][r] = p;
        ssum += p;
      }
#pragma unroll
      for (int o=1;o<16;o<<=1) ssum += __shfl_xor(ssum, o, 16);
      l_run[r] = l_run[r]*alpha[r] + ssum;
    }

#pragma unroll
    for (int ni=0;ni<8;ni++)
#pragma unroll
      for (int r=0;r<4;r++)
        Ps[(w*16 + quad*4 + r)*136 + ni*16 + lr] = bf16_1(sc[ni][r]);

#pragma unroll
    for (int nd=0;nd<4;nd++)
#pragma unroll
      for (int r=0;r<4;r++) oacc[nd][r] *= alpha[r];

    __builtin_amdgcn_s_setprio(1);
#pragma unroll
    for (int kk=0;kk<4;kk++) {
      FragU aP;
      aP.u = *(const uint4*)&Ps[(w*16 + lr)*136 + kk*32 + quad*8];
#pragma unroll
      for (int nd=0;nd<4;nd++) {
        FragU bV;
        bV.u = *(const uint4*)&Vts[(nd*16+lr)*136 + kk*32 + quad*8];
        oacc[nd] = __builtin_amdgcn_mfma_f32_16x16x32_bf16(aP.v, bV.v, oacc[nd], 0,0,0);
      }
    }
    __builtin_amdgcn_s_setprio(0);
  }
#undef PREF

#pragma unroll
  for (int r=0;r<4;r++) {
    const float rs = 1.0f / l_run[r];
    const int l = quad*4 + r;
#pragma unroll
    for (int nd=0;nd<4;nd++)
      attn_out[((size_t)(bk*16 + l))*512 + h*64 + nd*16 + lr] = bf16_1(oacc[nd][r] * rs);
  }
}

// ---------------- Kernel 3: out = attn_out(4096x512,bf16) @ Wob^T (round-0 proven) ----------------
__global__ __launch_bounds__(256)
void oproj_kernel(const uint16_t* __restrict__ Ab, const uint16_t* __restrict__ Wob,
                  float* __restrict__ out)
{
  __shared__ __align__(16) uint16_t As[128*72];
  __shared__ __align__(16) uint16_t Bs[128*72];
  const int t = threadIdx.x;
  const int m0 = (blockIdx.x >> 2) * 128;
  const int n0 = (blockIdx.x & 3) * 128;
  const int lane = t & 63, wv = t >> 6;
  const int quad = lane >> 4, lr = lane & 15;
  const int wm = wv >> 1, wn = wv & 1;

  f32x4 acc[4][4];
#pragma unroll
  for (int i=0;i<4;i++)
#pragma unroll
    for (int j=0;j<4;j++) acc[i][j] = (f32x4){0.f,0.f,0.f,0.f};

  const int srow = t >> 3, sseg = t & 7;
  for (int kb = 0; kb < 8; ++kb) {
#pragma unroll
    for (int j = 0; j < 4; ++j) {
      const int row = srow + 32*j;
      *(uint4*)&As[row*72 + sseg*8] = *(const uint4*)&Ab [(size_t)(m0+row)*512 + kb*64 + sseg*8];
      *(uint4*)&Bs[row*72 + sseg*8] = *(const uint4*)&Wob[(size_t)(n0+row)*512 + kb*64 + sseg*8];
    }
    __syncthreads();
#pragma unroll
    for (int kk = 0; kk < 2; ++kk) {
      const int c = kk*4 + quad;
      FragU aF[4], bF[4];
#pragma unroll
      for (int mi=0;mi<4;mi++) aF[mi].u = *(const uint4*)&As[(wm*64+mi*16+lr)*72 + c*8];
#pragma unroll
      for (int ni=0;ni<4;ni++) bF[ni].u = *(const uint4*)&Bs[(wn*64+ni*16+lr)*72 + c*8];
#pragma unroll
      for (int mi=0;mi<4;mi++)
#pragma unroll
        for (int ni=0;ni<4;ni++)
          acc[mi][ni] = __builtin_amdgcn_mfma_f32_16x16x32_bf16(aF[mi].v, bF[ni].v, acc[mi][ni], 0,0,0);
    }
    __syncthreads();
  }
#pragma unroll
  for (int mi=0;mi<4;mi++)
#pragma unroll
    for (int r=0;r<4;r++)
#pragma unroll
      for (int ni=0;ni<4;ni++)
        out[(size_t)(m0 + wm*64 + mi*16 + quad*4 + r)*512 + n0 + wn*64 + ni*16 + lr] = acc[mi][ni][r];
}

// ---------------- launch ----------------
extern "C" void kernel_launch(void* const* d_in, const int* in_sizes, int n_in,
                              void* d_out, int out_size, void* d_ws, size_t ws_size,
                              hipStream_t stream)
{
  const float* spike   = (const float*)d_in[0];
  const int*   offsets = (const int*)d_in[1];
  const int*   lengths = (const int*)d_in[2];
  const float* cosT    = (const float*)d_in[3];
  const float* sinT    = (const float*)d_in[4];
  const float* latent  = (const float*)d_in[5];
  const float* Wq      = (const float*)d_in[6];
  const float* Wk      = (const float*)d_in[7];
  const float* Wv      = (const float*)d_in[8];
  const float* Wo      = (const float*)d_in[9];
  float* out = (float*)d_out;

  char* ws = (char*)d_ws;
  float*    xq   = (float*)ws;                                  // 64 KB reserved
  uint4*    Wsw  = (uint4*)(ws + 65536);                        // 256 KB
  uint4*    Wob  = (uint4*)(ws + 65536 + 262144);               // 512 KB
  uint16_t* Kbuf = (uint16_t*)(ws + 1048576);                   // 32 MB
  uint16_t* Vt   = (uint16_t*)(ws + 1048576 + 33554432ull);     // 32 MB
  uint16_t* attn_out = (uint16_t*)(ws + 1048576 + 67108864ull); // 4 MB

  hipLaunchKernelGGL(prep_kernel,   dim3(704),  dim3(256), 0, stream,
                     latent, Wq, Wk, Wv, Wo, xq, Wsw, Wob);
  hipLaunchKernelGGL(kvproj_kernel, dim3(2048), dim3(256), 0, stream,
                     spike, offsets, cosT, sinT, Wsw, lengths, Kbuf, Vt);
  hipLaunchKernelGGL(attn_kernel,   dim3(512),  dim3(256), 0, stream,
                     xq, Kbuf, Vt, lengths, attn_out);
  hipLaunchKernelGGL(oproj_kernel,  dim3(128),  dim3(256), 0, stream,
                     attn_out, (const uint16_t*)Wob, out);
}